// Round 23
// baseline (144.330 us; speedup 1.0000x reference)
//
#include <hip/hip_runtime.h>
#include <hip/hip_bf16.h>
#include <hip/hip_fp16.h>

#define CH 64
#define RPB 128       // rows per bucket
#define RPB_SH 7
#define MAXNB 800     // max buckets supported by LDS arrays
#define NGRP 8        // reservation counter shards
#define SUBCAP 600    // per-(bucket,group) capacity (mean 512 + ~4 sigma)
#define CAPG (NGRP * SUBCAP)  // 4800 records per bucket region
#define BATCH 3072    // fill staging batch (LDS) -> 36.4 KB/block
#define SPILLMAX 16384
#define FILL_BLOCKS 521
#define GEMM_PHYS 503
// FILL_BLOCKS + GEMM_PHYS = 1024 blocks, all co-resident (4/CU)

typedef __attribute__((ext_vector_type(8))) _Float16 half8;
typedef __attribute__((ext_vector_type(4))) float f32x4;

// record: rec.x = (local_row << 24) | (col << 7)  [col*128 = xw row byte offset]
//         rec.y = fp32 val bits
#define COLOFF_MASK 0x00FFFF80

// ---------------------------------------------------------------------------
// Merged kernel with DYNAMIC gemm work-sharing: fill blocks run the sharded
// reservation-fill, then fall through to the gemm loop; gemm blocks go
// straight there. 32-row gemm groups are handed out by a global atomic.
// ---------------------------------------------------------------------------
__global__ __launch_bounds__(512) void gemm_fill_kernel(
    const float* __restrict__ x, const float* __restrict__ wc,
    const float* __restrict__ wl, __half* __restrict__ xwh,
    float* __restrict__ out, int n,
    const int* __restrict__ r1, const int* __restrict__ c1, const float* __restrict__ v1,
    const int* __restrict__ r2, const int* __restrict__ c2, const float* __restrict__ v2,
    int* __restrict__ gcur, int* __restrict__ spillcnt, int* __restrict__ gwork,
    int4* __restrict__ spill, int2* __restrict__ ebuf, int nnz, int nb) {
  __shared__ int2 stash[BATCH];           // 24 KB
  __shared__ unsigned short sbuck[BATCH]; // 6 KB
  __shared__ int hist[MAXNB];             // 3.2 KB
  __shared__ int rbase[MAXNB];            // 3.2 KB
  __shared__ int gsh;

  const int tid = threadIdx.x;

  if (blockIdx.x < (unsigned)FILL_BLOCKS) {
    const int grp = (int)(blockIdx.x & (NGRP - 1));  // counter shard
    const int tot = 2 * nnz;
    const int nbatches = (tot + BATCH - 1) / BATCH;
    for (int bt = blockIdx.x; bt < nbatches; bt += FILL_BLOCKS) {
      for (int i = tid; i < nb; i += 512) hist[i] = 0;
      __syncthreads();

      const int e0 = bt * BATCH;
      const int m = min(BATCH, tot - e0);
      for (int i = tid; i < m; i += 512) {
        const int e = e0 + i;
        int r, c;
        float v;
        if (e < nnz) {
          r = r1[e]; c = c1[e]; v = v1[e];
        } else {
          r = r2[e - nnz]; c = c2[e - nnz]; v = v2[e - nnz];
        }
        const int b = r >> RPB_SH;
        stash[i] = make_int2(((r & (RPB - 1)) << 24) | (c << 7), __float_as_int(v));
        sbuck[i] = (unsigned short)b;
        atomicAdd(&hist[b], 1);
      }
      __syncthreads();

      for (int b = tid; b < nb; b += 512) {
        const int c = hist[b];
        rbase[b] = c ? atomicAdd(&gcur[grp * nb + b], c) : 0;
        hist[b] = 0;  // reuse as local placement cursor
      }
      __syncthreads();

      for (int i = tid; i < m; i += 512) {
        const int b = sbuck[i];
        const int2 rec = stash[i];
        const int p = rbase[b] + atomicAdd(&hist[b], 1);
        if (p < SUBCAP) {
          ebuf[(size_t)b * CAPG + grp * SUBCAP + p] = rec;
        } else {
          const int sp = atomicAdd(spillcnt, 1);
          if (sp < SPILLMAX)
            spill[sp] = make_int4(b * RPB + (rec.x >> 24), rec.x & COLOFF_MASK,
                                  rec.y, 0);
        }
      }
      __syncthreads();
    }
    // fall through: join the gemm work pool
  }

  // ---- GEMM path (all blocks): dynamic 32-row groups via atomic counter ----
  const int t256 = tid & 255;
  const int lane = t256 & 63;
  const int wv = t256 >> 6;
  const int mat = wv >> 1;   // 0: conv, 1: lin
  const int tile = wv & 1;   // row-tile within 32-row group
  const float* __restrict__ W = mat ? wl : wc;

  const int i16 = lane & 15;
  const int kseg = lane >> 4;

  half8 bhi[4][2], blo[4][2];
#pragma unroll
  for (int nt = 0; nt < 4; ++nt)
#pragma unroll
    for (int kk = 0; kk < 2; ++kk)
#pragma unroll
      for (int j = 0; j < 8; ++j) {
        const float w = W[(kk * 32 + kseg * 8 + j) * CH + nt * 16 + i16];
        const _Float16 hh = (_Float16)w;
        bhi[nt][kk][j] = hh;
        blo[nt][kk][j] = (_Float16)(w - (float)hh);
      }

  const int ngroups = (n + 31) >> 5;
  for (;;) {
    __syncthreads();
    if (tid == 0) gsh = atomicAdd(gwork, 2);
    __syncthreads();
    const int gbase = gsh;
    if (gbase >= ngroups) break;
    const int g = gbase + (tid >> 8);  // each 256-half takes one group
    if (g >= ngroups) continue;

    const int base = g * 32 + tile * 16;
    const int row = base + i16;
    const int rowc = (row < n) ? row : (n - 1);
    const float* xp = x + (size_t)rowc * CH + kseg * 8;

    float af[16];
    {
      const float4 p0 = *(const float4*)(xp);
      const float4 p1 = *(const float4*)(xp + 4);
      const float4 q0 = *(const float4*)(xp + 32);
      const float4 q1 = *(const float4*)(xp + 36);
      af[0] = p0.x; af[1] = p0.y; af[2] = p0.z; af[3] = p0.w;
      af[4] = p1.x; af[5] = p1.y; af[6] = p1.z; af[7] = p1.w;
      af[8] = q0.x; af[9] = q0.y; af[10] = q0.z; af[11] = q0.w;
      af[12] = q1.x; af[13] = q1.y; af[14] = q1.z; af[15] = q1.w;
    }
    half8 ahi[2], alo[2];
#pragma unroll
    for (int kk = 0; kk < 2; ++kk)
#pragma unroll
      for (int j = 0; j < 8; ++j) {
        const float f = af[kk * 8 + j];
        const _Float16 hh = (_Float16)f;
        ahi[kk][j] = hh;
        alo[kk][j] = (_Float16)(f - (float)hh);
      }

    f32x4 acc[4];
#pragma unroll
    for (int nt = 0; nt < 4; ++nt) {
      f32x4 a = {0.f, 0.f, 0.f, 0.f};
#pragma unroll
      for (int kk = 0; kk < 2; ++kk) {
        a = __builtin_amdgcn_mfma_f32_16x16x32_f16(ahi[kk], bhi[nt][kk], a, 0, 0, 0);
        a = __builtin_amdgcn_mfma_f32_16x16x32_f16(alo[kk], bhi[nt][kk], a, 0, 0, 0);
        a = __builtin_amdgcn_mfma_f32_16x16x32_f16(ahi[kk], blo[nt][kk], a, 0, 0, 0);
      }
      acc[nt] = a;
    }

    if (mat == 0) {
#pragma unroll
      for (int nt = 0; nt < 4; ++nt)
#pragma unroll
        for (int r = 0; r < 4; ++r) {
          const int orow = base + kseg * 4 + r;
          if (orow < n)
            xwh[(size_t)orow * CH + nt * 16 + i16] = __float2half(acc[nt][r]);
        }
    } else {
#pragma unroll
      for (int nt = 0; nt < 4; ++nt)
#pragma unroll
        for (int r = 0; r < 4; ++r) {
          const int orow = base + kseg * 4 + r;
          if (orow < n)
            out[(size_t)orow * CH + nt * 16 + i16] = acc[nt][r];
        }
    }
  }
}

// ---------------------------------------------------------------------------
// Fused sort+gather (R20, proven): register-staged sort + 8-lane-group gather.
// ---------------------------------------------------------------------------
union U8 {
  uint4 u4;
  __half h[8];
};

__device__ __forceinline__ void edge_fma(float* a, const U8& u, float v) {
#pragma unroll
  for (int k = 0; k < 8; ++k)
    a[k] = fmaf(v, __half2float(u.h[k]), a[k]);
}

#define PERG 2  // ceil(SUBCAP/512) register slots per group

__global__ __launch_bounds__(512, 8) void sortgather2_kernel(
    const int* __restrict__ gcur, const int2* __restrict__ ebuf,
    const char* __restrict__ xwbytes, float4* __restrict__ outf4,
    const int* __restrict__ spillcnt, const int4* __restrict__ spill,
    int n, int nb) {
  __shared__ int2 raw[CAPG];      // 38.4 KB (sorted records)
  __shared__ int hist[RPB];       // per-row counts (persist for gather)
  __shared__ int rowstart[RPB];
  __shared__ int cur[RPB];
  const int tid = threadIdx.x;
  const int b = blockIdx.x;
  const int beg = b * CAPG;

  if (tid < RPB) hist[tid] = 0;
  __syncthreads();

  // pass 1: load records into registers (single global read) + histogram
  int2 myrec[NGRP * PERG];
#pragma unroll
  for (int g = 0; g < NGRP; ++g) {
    const int cg = min(gcur[g * nb + b], SUBCAP);
#pragma unroll
    for (int j = 0; j < PERG; ++j) {
      const int i = j * 512 + tid;
      const bool ok = i < cg;
      int2 rec = ok ? ebuf[beg + g * SUBCAP + i] : make_int2(-1, 0);
      myrec[g * PERG + j] = rec;
      if (ok) atomicAdd(&hist[rec.x >> 24], 1);
    }
  }
  __syncthreads();

  // exclusive scan of hist into rowstart (Hillis-Steele in cur)
  int v = 0;
  if (tid < RPB) {
    v = hist[tid];
    cur[tid] = v;
  }
  __syncthreads();
  for (int off = 1; off < RPB; off <<= 1) {
    int t = 0;
    if (tid < RPB && tid >= off) t = cur[tid - off];
    __syncthreads();
    if (tid < RPB) cur[tid] += t;
    __syncthreads();
  }
  if (tid < RPB) {
    rowstart[tid] = cur[tid] - v;  // exclusive
    cur[tid] = cur[tid] - v;       // placement cursor
  }
  __syncthreads();

  // pass 2: scatter from registers into sorted LDS raw[]
#pragma unroll
  for (int g = 0; g < NGRP; ++g)
#pragma unroll
    for (int j = 0; j < PERG; ++j) {
      const int2 rec = myrec[g * PERG + j];
      if (rec.x >= 0) {
        const int pos = atomicAdd(&cur[rec.x >> 24], 1);
        raw[pos] = rec;
      }
    }
  __syncthreads();

  // ---- gather phase: 8 waves x 16 rows, records from LDS ----
  const int lane = tid & 63;
  const int g8 = lane >> 3;       // edge slot 0..7
  const int l8 = lane & 7;        // channel-quad index
  const int l8b = l8 << 4;        // byte offset within xw row
  const int wv = tid >> 6;        // wave 0..7
  const int sc = min(*spillcnt, SPILLMAX);

  for (int rl = wv; rl < RPB; rl += 8) {
    const int row = b * RPB + rl;
    if (row >= n) continue;

    float a[8];
#pragma unroll
    for (int k = 0; k < 8; ++k) a[k] = 0.f;

    const int rbeg = rowstart[rl];
    const int rend = rbeg + hist[rl];

    int e = rbeg;
    for (; e + 32 <= rend; e += 32) {
      int2 rc[4];
      U8 u[4];
#pragma unroll
      for (int q = 0; q < 4; ++q) rc[q] = raw[e + q * 8 + g8];
#pragma unroll
      for (int q = 0; q < 4; ++q)
        u[q].u4 = *(const uint4*)(xwbytes + (rc[q].x & COLOFF_MASK) + l8b);
#pragma unroll
      for (int q = 0; q < 4; ++q) edge_fma(a, u[q], __int_as_float(rc[q].y));
    }
    for (; e + 16 <= rend; e += 16) {
      const int2 rc0 = raw[e + g8];
      const int2 rc1 = raw[e + 8 + g8];
      U8 u0, u1;
      u0.u4 = *(const uint4*)(xwbytes + (rc0.x & COLOFF_MASK) + l8b);
      u1.u4 = *(const uint4*)(xwbytes + (rc1.x & COLOFF_MASK) + l8b);
      edge_fma(a, u0, __int_as_float(rc0.y));
      edge_fma(a, u1, __int_as_float(rc1.y));
    }
    for (; e < rend; e += 8) {
      const int idx = e + g8;
      const bool ok = idx < rend;
      const int2 rc = raw[ok ? idx : (rend - 1)];
      U8 u;
      u.u4 = *(const uint4*)(xwbytes + (rc.x & COLOFF_MASK) + l8b);
      edge_fma(a, u, ok ? __int_as_float(rc.y) : 0.f);
    }

    if (sc > 0) {  // spill pass (empty in practice; uniform branch)
      for (int s = 0; s < sc; ++s) {
        const int4 r = spill[s];
        if (r.x == row && g8 == 0) {
          U8 u;
          u.u4 = *(const uint4*)(xwbytes + r.y + l8b);
          edge_fma(a, u, __int_as_float(r.z));
        }
      }
    }

    // butterfly merge across the 8 groups
#pragma unroll
    for (int k = 0; k < 8; ++k) {
      a[k] += __shfl_xor(a[k], 8, 64);
      a[k] += __shfl_xor(a[k], 16, 64);
      a[k] += __shfl_xor(a[k], 32, 64);
    }

    if (lane < 8) {  // g8 == 0: l8 = lane
      const float4 lin0 = outf4[(size_t)row * 16 + 2 * l8];
      const float4 lin1 = outf4[(size_t)row * 16 + 2 * l8 + 1];
      float4 o0, o1;
      o0.x = 1.f / (1.f + __expf(-(lin0.x + a[0])));
      o0.y = 1.f / (1.f + __expf(-(lin0.y + a[1])));
      o0.z = 1.f / (1.f + __expf(-(lin0.z + a[2])));
      o0.w = 1.f / (1.f + __expf(-(lin0.w + a[3])));
      o1.x = 1.f / (1.f + __expf(-(lin1.x + a[4])));
      o1.y = 1.f / (1.f + __expf(-(lin1.y + a[5])));
      o1.z = 1.f / (1.f + __expf(-(lin1.z + a[6])));
      o1.w = 1.f / (1.f + __expf(-(lin1.w + a[7])));
      outf4[(size_t)row * 16 + 2 * l8] = o0;
      outf4[(size_t)row * 16 + 2 * l8 + 1] = o1;
    }
  }
}

// ---------------------------------------------------------------------------
// Fallback path (ws too small): gemm-only + atomic scatter + sigmoid.
// ---------------------------------------------------------------------------
__global__ __launch_bounds__(256) void gemm_kernel(
    const float* __restrict__ x, const float* __restrict__ wc,
    const float* __restrict__ wl, __half* __restrict__ xwh,
    float* __restrict__ out, int n) {
  const int lane = threadIdx.x & 63;
  const int wv = threadIdx.x >> 6;
  const int mat = wv >> 1;
  const int tile = wv & 1;
  const float* __restrict__ W = mat ? wl : wc;
  const int i16 = lane & 15;
  const int kseg = lane >> 4;

  half8 bhi[4][2], blo[4][2];
#pragma unroll
  for (int nt = 0; nt < 4; ++nt)
#pragma unroll
    for (int kk = 0; kk < 2; ++kk)
#pragma unroll
      for (int j = 0; j < 8; ++j) {
        const float w = W[(kk * 32 + kseg * 8 + j) * CH + nt * 16 + i16];
        const _Float16 hh = (_Float16)w;
        bhi[nt][kk][j] = hh;
        blo[nt][kk][j] = (_Float16)(w - (float)hh);
      }

  const int ngroups = (n + 31) >> 5;
  for (int g = blockIdx.x; g < ngroups; g += gridDim.x) {
    const int base = g * 32 + tile * 16;
    const int row = base + i16;
    const int rowc = (row < n) ? row : (n - 1);
    const float* xp = x + (size_t)rowc * CH + kseg * 8;
    float af[16];
    {
      const float4 p0 = *(const float4*)(xp);
      const float4 p1 = *(const float4*)(xp + 4);
      const float4 q0 = *(const float4*)(xp + 32);
      const float4 q1 = *(const float4*)(xp + 36);
      af[0] = p0.x; af[1] = p0.y; af[2] = p0.z; af[3] = p0.w;
      af[4] = p1.x; af[5] = p1.y; af[6] = p1.z; af[7] = p1.w;
      af[8] = q0.x; af[9] = q0.y; af[10] = q0.z; af[11] = q0.w;
      af[12] = q1.x; af[13] = q1.y; af[14] = q1.z; af[15] = q1.w;
    }
    half8 ahi[2], alo[2];
#pragma unroll
    for (int kk = 0; kk < 2; ++kk)
#pragma unroll
      for (int j = 0; j < 8; ++j) {
        const float f = af[kk * 8 + j];
        const _Float16 hh = (_Float16)f;
        ahi[kk][j] = hh;
        alo[kk][j] = (_Float16)(f - (float)hh);
      }
    f32x4 acc[4];
#pragma unroll
    for (int nt = 0; nt < 4; ++nt) {
      f32x4 a = {0.f, 0.f, 0.f, 0.f};
#pragma unroll
      for (int kk = 0; kk < 2; ++kk) {
        a = __builtin_amdgcn_mfma_f32_16x16x32_f16(ahi[kk], bhi[nt][kk], a, 0, 0, 0);
        a = __builtin_amdgcn_mfma_f32_16x16x32_f16(alo[kk], bhi[nt][kk], a, 0, 0, 0);
        a = __builtin_amdgcn_mfma_f32_16x16x32_f16(ahi[kk], blo[nt][kk], a, 0, 0, 0);
      }
      acc[nt] = a;
    }
    if (mat == 0) {
#pragma unroll
      for (int nt = 0; nt < 4; ++nt)
#pragma unroll
        for (int r = 0; r < 4; ++r) {
          const int orow = base + kseg * 4 + r;
          if (orow < n)
            xwh[(size_t)orow * CH + nt * 16 + i16] = __float2half(acc[nt][r]);
        }
    } else {
#pragma unroll
      for (int nt = 0; nt < 4; ++nt)
#pragma unroll
        for (int r = 0; r < 4; ++r) {
          const int orow = base + kseg * 4 + r;
          if (orow < n)
            out[(size_t)orow * CH + nt * 16 + i16] = acc[nt][r];
        }
    }
  }
}

__global__ __launch_bounds__(256) void scatter_kernel(
    const int* __restrict__ rows, const int* __restrict__ cols,
    const float* __restrict__ vals, const __half* __restrict__ xwh,
    float* __restrict__ out, int nnz) {
  const int lane = threadIdx.x & 63;
  const int wid = (blockIdx.x * blockDim.x + threadIdx.x) >> 6;
  const int nwaves = (gridDim.x * blockDim.x) >> 6;
  for (int k = wid; k < nnz; k += nwaves) {
    const float xv = __half2float(xwh[(size_t)cols[k] * CH + lane]);
    atomicAdd(&out[(size_t)rows[k] * CH + lane], vals[k] * xv);
  }
}

__global__ __launch_bounds__(256) void sigmoid_kernel(float* __restrict__ out, int n4) {
  const int i = blockIdx.x * blockDim.x + threadIdx.x;
  if (i < n4) {
    float4 v = reinterpret_cast<float4*>(out)[i];
    v.x = 1.f / (1.f + __expf(-v.x));
    v.y = 1.f / (1.f + __expf(-v.y));
    v.z = 1.f / (1.f + __expf(-v.z));
    v.w = 1.f / (1.f + __expf(-v.w));
    reinterpret_cast<float4*>(out)[i] = v;
  }
}

extern "C" void kernel_launch(void* const* d_in, const int* in_sizes, int n_in,
                              void* d_out, int out_size, void* d_ws, size_t ws_size,
                              hipStream_t stream) {
  const float* x         = (const float*)d_in[0];
  const int*   down_rows = (const int*)d_in[1];
  const int*   down_cols = (const int*)d_in[2];
  const float* down_vals = (const float*)d_in[3];
  const int*   up_rows   = (const int*)d_in[4];
  const int*   up_cols   = (const int*)d_in[5];
  const float* up_vals   = (const float*)d_in[6];
  const float* w_conv    = (const float*)d_in[7];
  const float* w_lin     = (const float*)d_in[8];

  const int n   = in_sizes[0] / CH;  // 100000
  const int nnz = in_sizes[1];       // 1600000
  const int nb  = (n + RPB - 1) / RPB;  // 782

  float* out = (float*)d_out;

  // ws layout (xw stored as fp16)
  char* p = (char*)d_ws;
  __half* xwh  = (__half*)p;  p += (size_t)n * CH * 2;
  int* gcur    = (int*)p;  p += (size_t)NGRP * nb * 4;
  int* spillc  = (int*)p;               // [0]=spill counter, [1]=gemm work counter
  int* gwork   = spillc + 1;
  p += 16;
  p = (char*)(((uintptr_t)p + 15) & ~(uintptr_t)15);
  int4* spill  = (int4*)p; p += (size_t)SPILLMAX * 16;
  int2* ebuf   = (int2*)p; p += (size_t)nb * CAPG * 8;
  const size_t need = (size_t)(p - (char*)d_ws);

  if (ws_size >= need && nb <= MAXNB && n < (1 << 17)) {
    (void)hipMemsetAsync(gcur, 0, (size_t)NGRP * nb * 4 + 16, stream);  // gcur+spillc+gwork
    gemm_fill_kernel<<<FILL_BLOCKS + GEMM_PHYS, 512, 0, stream>>>(
        x, w_conv, w_lin, xwh, out, n,
        down_rows, down_cols, down_vals, up_rows, up_cols, up_vals,
        gcur, spillc, gwork, spill, ebuf, nnz, nb);
    sortgather2_kernel<<<nb, 512, 0, stream>>>(
        gcur, ebuf, (const char*)xwh, (float4*)out, spillc, spill, n, nb);
  } else {
    gemm_kernel<<<1024, 256, 0, stream>>>(x, w_conv, w_lin, xwh, out, n);
    scatter_kernel<<<4096, 256, 0, stream>>>(down_rows, down_cols, down_vals, xwh, out, nnz);
    scatter_kernel<<<4096, 256, 0, stream>>>(up_rows, up_cols, up_vals, xwh, out, nnz);
    const int n4 = (n * CH) / 4;
    sigmoid_kernel<<<(n4 + 255) / 256, 256, 0, stream>>>(out, n4);
  }
}

// Round 24
// 123.287 us; speedup vs baseline: 1.1707x; 1.1707x over previous
//
#include <hip/hip_runtime.h>
#include <hip/hip_bf16.h>
#include <hip/hip_fp16.h>

#define CH 64
#define RPB 128       // rows per bucket
#define RPB_SH 7
#define MAXNB 800     // max buckets supported by LDS arrays
#define NGRP 8        // reservation counter shards
#define SUBCAP 600    // per-(bucket,group) capacity (mean 512 + ~4 sigma)
#define CAPG (NGRP * SUBCAP)  // 4800 records per bucket region
#define BATCH 3072    // fill staging batch (LDS) -> 36.4 KB/block
#define SPILLMAX 16384
#define FILL_BLOCKS 521
#define GEMM_PHYS 503
#define NVB (GEMM_PHYS * 2)

typedef __attribute__((ext_vector_type(8))) _Float16 half8;
typedef __attribute__((ext_vector_type(4))) float f32x4;

// record: rec.x = (local_row << 24) | (col << 7)  [col*128 = xw row byte offset]
//         rec.y = fp32 val bits
#define COLOFF_MASK 0x00FFFF80

// ---------------------------------------------------------------------------
// Merged kernel: blocks [0, FILL_BLOCKS) run the sharded reservation-fill;
// blocks [FILL_BLOCKS, FILL_BLOCKS+GEMM_PHYS) run the dual GEMM as two
// virtual 256-thread blocks.
// ---------------------------------------------------------------------------
__global__ __launch_bounds__(512) void gemm_fill_kernel(
    const float* __restrict__ x, const float* __restrict__ wc,
    const float* __restrict__ wl, __half* __restrict__ xwh,
    float* __restrict__ out, int n,
    const int* __restrict__ r1, const int* __restrict__ c1, const float* __restrict__ v1,
    const int* __restrict__ r2, const int* __restrict__ c2, const float* __restrict__ v2,
    int* __restrict__ gcur, int* __restrict__ spillcnt, int4* __restrict__ spill,
    int2* __restrict__ ebuf, int nnz, int nb) {
  __shared__ int2 stash[BATCH];           // 24 KB
  __shared__ unsigned short sbuck[BATCH]; // 6 KB
  __shared__ int hist[MAXNB];             // 3.2 KB
  __shared__ int rbase[MAXNB];            // 3.2 KB

  const int tid = threadIdx.x;

  if (blockIdx.x < (unsigned)FILL_BLOCKS) {
    const int grp = (int)(blockIdx.x & (NGRP - 1));  // counter shard
    const int tot = 2 * nnz;
    const int nbatches = (tot + BATCH - 1) / BATCH;
    for (int bt = blockIdx.x; bt < nbatches; bt += FILL_BLOCKS) {
      for (int i = tid; i < nb; i += 512) hist[i] = 0;
      __syncthreads();

      const int e0 = bt * BATCH;
      const int m = min(BATCH, tot - e0);
      for (int i = tid; i < m; i += 512) {
        const int e = e0 + i;
        int r, c;
        float v;
        if (e < nnz) {
          r = r1[e]; c = c1[e]; v = v1[e];
        } else {
          r = r2[e - nnz]; c = c2[e - nnz]; v = v2[e - nnz];
        }
        const int b = r >> RPB_SH;
        stash[i] = make_int2(((r & (RPB - 1)) << 24) | (c << 7), __float_as_int(v));
        sbuck[i] = (unsigned short)b;
        atomicAdd(&hist[b], 1);
      }
      __syncthreads();

      for (int b = tid; b < nb; b += 512) {
        const int c = hist[b];
        rbase[b] = c ? atomicAdd(&gcur[grp * nb + b], c) : 0;
        hist[b] = 0;  // reuse as local placement cursor
      }
      __syncthreads();

      for (int i = tid; i < m; i += 512) {
        const int b = sbuck[i];
        const int2 rec = stash[i];
        const int p = rbase[b] + atomicAdd(&hist[b], 1);
        if (p < SUBCAP) {
          ebuf[(size_t)b * CAPG + grp * SUBCAP + p] = rec;
        } else {
          const int sp = atomicAdd(spillcnt, 1);
          if (sp < SPILLMAX)
            spill[sp] = make_int4(b * RPB + (rec.x >> 24), rec.x & COLOFF_MASK,
                                  rec.y, 0);
        }
      }
      __syncthreads();
    }
    return;
  }

  // ---- GEMM path: virtual 256-thread block ----
  const int vb = (int)(blockIdx.x - FILL_BLOCKS) * 2 + (tid >> 8);
  const int t256 = tid & 255;
  const int lane = t256 & 63;
  const int wv = t256 >> 6;
  const int mat = wv >> 1;
  const int tile = wv & 1;
  const float* __restrict__ W = mat ? wl : wc;

  const int i16 = lane & 15;
  const int kseg = lane >> 4;

  half8 bhi[4][2], blo[4][2];
#pragma unroll
  for (int nt = 0; nt < 4; ++nt)
#pragma unroll
    for (int kk = 0; kk < 2; ++kk)
#pragma unroll
      for (int j = 0; j < 8; ++j) {
        const float w = W[(kk * 32 + kseg * 8 + j) * CH + nt * 16 + i16];
        const _Float16 hh = (_Float16)w;
        bhi[nt][kk][j] = hh;
        blo[nt][kk][j] = (_Float16)(w - (float)hh);
      }

  const int ngroups = (n + 31) >> 5;
  for (int g = vb; g < ngroups; g += NVB) {
    const int base = g * 32 + tile * 16;
    const int row = base + i16;
    const int rowc = (row < n) ? row : (n - 1);
    const float* xp = x + (size_t)rowc * CH + kseg * 8;

    float af[16];
    {
      const float4 p0 = *(const float4*)(xp);
      const float4 p1 = *(const float4*)(xp + 4);
      const float4 q0 = *(const float4*)(xp + 32);
      const float4 q1 = *(const float4*)(xp + 36);
      af[0] = p0.x; af[1] = p0.y; af[2] = p0.z; af[3] = p0.w;
      af[4] = p1.x; af[5] = p1.y; af[6] = p1.z; af[7] = p1.w;
      af[8] = q0.x; af[9] = q0.y; af[10] = q0.z; af[11] = q0.w;
      af[12] = q1.x; af[13] = q1.y; af[14] = q1.z; af[15] = q1.w;
    }
    half8 ahi[2], alo[2];
#pragma unroll
    for (int kk = 0; kk < 2; ++kk)
#pragma unroll
      for (int j = 0; j < 8; ++j) {
        const float f = af[kk * 8 + j];
        const _Float16 hh = (_Float16)f;
        ahi[kk][j] = hh;
        alo[kk][j] = (_Float16)(f - (float)hh);
      }

    f32x4 acc[4];
#pragma unroll
    for (int nt = 0; nt < 4; ++nt) {
      f32x4 a = {0.f, 0.f, 0.f, 0.f};
#pragma unroll
      for (int kk = 0; kk < 2; ++kk) {
        a = __builtin_amdgcn_mfma_f32_16x16x32_f16(ahi[kk], bhi[nt][kk], a, 0, 0, 0);
        a = __builtin_amdgcn_mfma_f32_16x16x32_f16(alo[kk], bhi[nt][kk], a, 0, 0, 0);
        a = __builtin_amdgcn_mfma_f32_16x16x32_f16(ahi[kk], blo[nt][kk], a, 0, 0, 0);
      }
      acc[nt] = a;
    }

    if (mat == 0) {
#pragma unroll
      for (int nt = 0; nt < 4; ++nt)
#pragma unroll
        for (int r = 0; r < 4; ++r) {
          const int orow = base + kseg * 4 + r;
          if (orow < n)
            xwh[(size_t)orow * CH + nt * 16 + i16] = __float2half(acc[nt][r]);
        }
    } else {
#pragma unroll
      for (int nt = 0; nt < 4; ++nt)
#pragma unroll
        for (int r = 0; r < 4; ++r) {
          const int orow = base + kseg * 4 + r;
          if (orow < n)
            out[(size_t)orow * CH + nt * 16 + i16] = acc[nt][r];
        }
    }
  }
}

// ---------------------------------------------------------------------------
// Fused sort+gather: register-staged sort + 8-lane-group gather (R20 winner).
// ---------------------------------------------------------------------------
union U8 {
  uint4 u4;
  __half h[8];
};

__device__ __forceinline__ void edge_fma(float* a, const U8& u, float v) {
#pragma unroll
  for (int k = 0; k < 8; ++k)
    a[k] = fmaf(v, __half2float(u.h[k]), a[k]);
}

#define PERG 2  // ceil(SUBCAP/512) register slots per group

__global__ __launch_bounds__(512, 8) void sortgather2_kernel(
    const int* __restrict__ gcur, const int2* __restrict__ ebuf,
    const char* __restrict__ xwbytes, float4* __restrict__ outf4,
    const int* __restrict__ spillcnt, const int4* __restrict__ spill,
    int n, int nb) {
  __shared__ int2 raw[CAPG];      // 38.4 KB (sorted records)
  __shared__ int hist[RPB];       // per-row counts (persist for gather)
  __shared__ int rowstart[RPB];
  __shared__ int cur[RPB];
  const int tid = threadIdx.x;
  const int b = blockIdx.x;
  const int beg = b * CAPG;

  if (tid < RPB) hist[tid] = 0;
  __syncthreads();

  // pass 1: load records into registers (single global read) + histogram
  int2 myrec[NGRP * PERG];
#pragma unroll
  for (int g = 0; g < NGRP; ++g) {
    const int cg = min(gcur[g * nb + b], SUBCAP);
#pragma unroll
    for (int j = 0; j < PERG; ++j) {
      const int i = j * 512 + tid;
      const bool ok = i < cg;
      int2 rec = ok ? ebuf[beg + g * SUBCAP + i] : make_int2(-1, 0);
      myrec[g * PERG + j] = rec;
      if (ok) atomicAdd(&hist[rec.x >> 24], 1);
    }
  }
  __syncthreads();

  // exclusive scan of hist into rowstart (Hillis-Steele in cur)
  int v = 0;
  if (tid < RPB) {
    v = hist[tid];
    cur[tid] = v;
  }
  __syncthreads();
  for (int off = 1; off < RPB; off <<= 1) {
    int t = 0;
    if (tid < RPB && tid >= off) t = cur[tid - off];
    __syncthreads();
    if (tid < RPB) cur[tid] += t;
    __syncthreads();
  }
  if (tid < RPB) {
    rowstart[tid] = cur[tid] - v;  // exclusive
    cur[tid] = cur[tid] - v;       // placement cursor
  }
  __syncthreads();

  // pass 2: scatter from registers into sorted LDS raw[]
#pragma unroll
  for (int g = 0; g < NGRP; ++g)
#pragma unroll
    for (int j = 0; j < PERG; ++j) {
      const int2 rec = myrec[g * PERG + j];
      if (rec.x >= 0) {
        const int pos = atomicAdd(&cur[rec.x >> 24], 1);
        raw[pos] = rec;
      }
    }
  __syncthreads();

  // ---- gather phase: 8 waves x 16 rows, records from LDS ----
  const int lane = tid & 63;
  const int g8 = lane >> 3;       // edge slot 0..7
  const int l8 = lane & 7;        // channel-quad index
  const int l8b = l8 << 4;        // byte offset within xw row
  const int wv = tid >> 6;        // wave 0..7
  const int sc = min(*spillcnt, SPILLMAX);

  for (int rl = wv; rl < RPB; rl += 8) {
    const int row = b * RPB + rl;
    if (row >= n) continue;

    float a[8];
#pragma unroll
    for (int k = 0; k < 8; ++k) a[k] = 0.f;

    const int rbeg = rowstart[rl];
    const int rend = rbeg + hist[rl];

    int e = rbeg;
    for (; e + 32 <= rend; e += 32) {
      int2 rc[4];
      U8 u[4];
#pragma unroll
      for (int q = 0; q < 4; ++q) rc[q] = raw[e + q * 8 + g8];
#pragma unroll
      for (int q = 0; q < 4; ++q)
        u[q].u4 = *(const uint4*)(xwbytes + (rc[q].x & COLOFF_MASK) + l8b);
#pragma unroll
      for (int q = 0; q < 4; ++q) edge_fma(a, u[q], __int_as_float(rc[q].y));
    }
    for (; e + 16 <= rend; e += 16) {
      const int2 rc0 = raw[e + g8];
      const int2 rc1 = raw[e + 8 + g8];
      U8 u0, u1;
      u0.u4 = *(const uint4*)(xwbytes + (rc0.x & COLOFF_MASK) + l8b);
      u1.u4 = *(const uint4*)(xwbytes + (rc1.x & COLOFF_MASK) + l8b);
      edge_fma(a, u0, __int_as_float(rc0.y));
      edge_fma(a, u1, __int_as_float(rc1.y));
    }
    for (; e < rend; e += 8) {
      const int idx = e + g8;
      const bool ok = idx < rend;
      const int2 rc = raw[ok ? idx : (rend - 1)];
      U8 u;
      u.u4 = *(const uint4*)(xwbytes + (rc.x & COLOFF_MASK) + l8b);
      edge_fma(a, u, ok ? __int_as_float(rc.y) : 0.f);
    }

    if (sc > 0) {  // spill pass (empty in practice; uniform branch)
      for (int s = 0; s < sc; ++s) {
        const int4 r = spill[s];
        if (r.x == row && g8 == 0) {
          U8 u;
          u.u4 = *(const uint4*)(xwbytes + r.y + l8b);
          edge_fma(a, u, __int_as_float(r.z));
        }
      }
    }

    // butterfly merge across the 8 groups
#pragma unroll
    for (int k = 0; k < 8; ++k) {
      a[k] += __shfl_xor(a[k], 8, 64);
      a[k] += __shfl_xor(a[k], 16, 64);
      a[k] += __shfl_xor(a[k], 32, 64);
    }

    if (lane < 8) {  // g8 == 0: l8 = lane
      const float4 lin0 = outf4[(size_t)row * 16 + 2 * l8];
      const float4 lin1 = outf4[(size_t)row * 16 + 2 * l8 + 1];
      float4 o0, o1;
      o0.x = 1.f / (1.f + __expf(-(lin0.x + a[0])));
      o0.y = 1.f / (1.f + __expf(-(lin0.y + a[1])));
      o0.z = 1.f / (1.f + __expf(-(lin0.z + a[2])));
      o0.w = 1.f / (1.f + __expf(-(lin0.w + a[3])));
      o1.x = 1.f / (1.f + __expf(-(lin1.x + a[4])));
      o1.y = 1.f / (1.f + __expf(-(lin1.y + a[5])));
      o1.z = 1.f / (1.f + __expf(-(lin1.z + a[6])));
      o1.w = 1.f / (1.f + __expf(-(lin1.w + a[7])));
      outf4[(size_t)row * 16 + 2 * l8] = o0;
      outf4[(size_t)row * 16 + 2 * l8 + 1] = o1;
    }
  }
}

// ---------------------------------------------------------------------------
// Fallback path (ws too small): gemm-only + atomic scatter + sigmoid.
// ---------------------------------------------------------------------------
__global__ __launch_bounds__(256) void gemm_kernel(
    const float* __restrict__ x, const float* __restrict__ wc,
    const float* __restrict__ wl, __half* __restrict__ xwh,
    float* __restrict__ out, int n) {
  const int lane = threadIdx.x & 63;
  const int wv = threadIdx.x >> 6;
  const int mat = wv >> 1;
  const int tile = wv & 1;
  const float* __restrict__ W = mat ? wl : wc;
  const int i16 = lane & 15;
  const int kseg = lane >> 4;

  half8 bhi[4][2], blo[4][2];
#pragma unroll
  for (int nt = 0; nt < 4; ++nt)
#pragma unroll
    for (int kk = 0; kk < 2; ++kk)
#pragma unroll
      for (int j = 0; j < 8; ++j) {
        const float w = W[(kk * 32 + kseg * 8 + j) * CH + nt * 16 + i16];
        const _Float16 hh = (_Float16)w;
        bhi[nt][kk][j] = hh;
        blo[nt][kk][j] = (_Float16)(w - (float)hh);
      }

  const int ngroups = (n + 31) >> 5;
  for (int g = blockIdx.x; g < ngroups; g += gridDim.x) {
    const int base = g * 32 + tile * 16;
    const int row = base + i16;
    const int rowc = (row < n) ? row : (n - 1);
    const float* xp = x + (size_t)rowc * CH + kseg * 8;
    float af[16];
    {
      const float4 p0 = *(const float4*)(xp);
      const float4 p1 = *(const float4*)(xp + 4);
      const float4 q0 = *(const float4*)(xp + 32);
      const float4 q1 = *(const float4*)(xp + 36);
      af[0] = p0.x; af[1] = p0.y; af[2] = p0.z; af[3] = p0.w;
      af[4] = p1.x; af[5] = p1.y; af[6] = p1.z; af[7] = p1.w;
      af[8] = q0.x; af[9] = q0.y; af[10] = q0.z; af[11] = q0.w;
      af[12] = q1.x; af[13] = q1.y; af[14] = q1.z; af[15] = q1.w;
    }
    half8 ahi[2], alo[2];
#pragma unroll
    for (int kk = 0; kk < 2; ++kk)
#pragma unroll
      for (int j = 0; j < 8; ++j) {
        const float f = af[kk * 8 + j];
        const _Float16 hh = (_Float16)f;
        ahi[kk][j] = hh;
        alo[kk][j] = (_Float16)(f - (float)hh);
      }
    f32x4 acc[4];
#pragma unroll
    for (int nt = 0; nt < 4; ++nt) {
      f32x4 a = {0.f, 0.f, 0.f, 0.f};
#pragma unroll
      for (int kk = 0; kk < 2; ++kk) {
        a = __builtin_amdgcn_mfma_f32_16x16x32_f16(ahi[kk], bhi[nt][kk], a, 0, 0, 0);
        a = __builtin_amdgcn_mfma_f32_16x16x32_f16(alo[kk], bhi[nt][kk], a, 0, 0, 0);
        a = __builtin_amdgcn_mfma_f32_16x16x32_f16(ahi[kk], blo[nt][kk], a, 0, 0, 0);
      }
      acc[nt] = a;
    }
    if (mat == 0) {
#pragma unroll
      for (int nt = 0; nt < 4; ++nt)
#pragma unroll
        for (int r = 0; r < 4; ++r) {
          const int orow = base + kseg * 4 + r;
          if (orow < n)
            xwh[(size_t)orow * CH + nt * 16 + i16] = __float2half(acc[nt][r]);
        }
    } else {
#pragma unroll
      for (int nt = 0; nt < 4; ++nt)
#pragma unroll
        for (int r = 0; r < 4; ++r) {
          const int orow = base + kseg * 4 + r;
          if (orow < n)
            out[(size_t)orow * CH + nt * 16 + i16] = acc[nt][r];
        }
    }
  }
}

__global__ __launch_bounds__(256) void scatter_kernel(
    const int* __restrict__ rows, const int* __restrict__ cols,
    const float* __restrict__ vals, const __half* __restrict__ xwh,
    float* __restrict__ out, int nnz) {
  const int lane = threadIdx.x & 63;
  const int wid = (blockIdx.x * blockDim.x + threadIdx.x) >> 6;
  const int nwaves = (gridDim.x * blockDim.x) >> 6;
  for (int k = wid; k < nnz; k += nwaves) {
    const float xv = __half2float(xwh[(size_t)cols[k] * CH + lane]);
    atomicAdd(&out[(size_t)rows[k] * CH + lane], vals[k] * xv);
  }
}

__global__ __launch_bounds__(256) void sigmoid_kernel(float* __restrict__ out, int n4) {
  const int i = blockIdx.x * blockDim.x + threadIdx.x;
  if (i < n4) {
    float4 v = reinterpret_cast<float4*>(out)[i];
    v.x = 1.f / (1.f + __expf(-v.x));
    v.y = 1.f / (1.f + __expf(-v.y));
    v.z = 1.f / (1.f + __expf(-v.z));
    v.w = 1.f / (1.f + __expf(-v.w));
    reinterpret_cast<float4*>(out)[i] = v;
  }
}

extern "C" void kernel_launch(void* const* d_in, const int* in_sizes, int n_in,
                              void* d_out, int out_size, void* d_ws, size_t ws_size,
                              hipStream_t stream) {
  const float* x         = (const float*)d_in[0];
  const int*   down_rows = (const int*)d_in[1];
  const int*   down_cols = (const int*)d_in[2];
  const float* down_vals = (const float*)d_in[3];
  const int*   up_rows   = (const int*)d_in[4];
  const int*   up_cols   = (const int*)d_in[5];
  const float* up_vals   = (const float*)d_in[6];
  const float* w_conv    = (const float*)d_in[7];
  const float* w_lin     = (const float*)d_in[8];

  const int n   = in_sizes[0] / CH;  // 100000
  const int nnz = in_sizes[1];       // 1600000
  const int nb  = (n + RPB - 1) / RPB;  // 782

  float* out = (float*)d_out;

  // ws layout (xw stored as fp16)
  char* p = (char*)d_ws;
  __half* xwh  = (__half*)p;  p += (size_t)n * CH * 2;
  int* gcur    = (int*)p;  p += (size_t)NGRP * nb * 4;
  int* spillc  = (int*)p;  p += 16;           // spill counter (+pad)
  p = (char*)(((uintptr_t)p + 15) & ~(uintptr_t)15);
  int4* spill  = (int4*)p; p += (size_t)SPILLMAX * 16;
  int2* ebuf   = (int2*)p; p += (size_t)nb * CAPG * 8;
  const size_t need = (size_t)(p - (char*)d_ws);

  if (ws_size >= need && nb <= MAXNB && n < (1 << 17)) {
    (void)hipMemsetAsync(gcur, 0, (size_t)NGRP * nb * 4 + 16, stream);
    gemm_fill_kernel<<<FILL_BLOCKS + GEMM_PHYS, 512, 0, stream>>>(
        x, w_conv, w_lin, xwh, out, n,
        down_rows, down_cols, down_vals, up_rows, up_cols, up_vals,
        gcur, spillc, spill, ebuf, nnz, nb);
    sortgather2_kernel<<<nb, 512, 0, stream>>>(
        gcur, ebuf, (const char*)xwh, (float4*)out, spillc, spill, n, nb);
  } else {
    gemm_kernel<<<1024, 256, 0, stream>>>(x, w_conv, w_lin, xwh, out, n);
    scatter_kernel<<<4096, 256, 0, stream>>>(down_rows, down_cols, down_vals, xwh, out, nnz);
    scatter_kernel<<<4096, 256, 0, stream>>>(up_rows, up_cols, up_vals, xwh, out, nnz);
    const int n4 = (n * CH) / 4;
    sigmoid_kernel<<<(n4 + 255) / 256, 256, 0, stream>>>(out, n4);
  }
}